// Round 16
// baseline (231.060 us; speedup 1.0000x reference)
//
#include <hip/hip_runtime.h>

#define NB 4
#define NH 16
#define NSQ 1024
#define NSKV 1024
#define ND 64

typedef __attribute__((ext_vector_type(8))) short short8;
typedef __attribute__((ext_vector_type(4))) short short4v;
typedef __attribute__((ext_vector_type(4))) float f32x4;
typedef __attribute__((ext_vector_type(4))) int int4v;
typedef __attribute__((ext_vector_type(4))) unsigned int uint4v;
typedef __attribute__((ext_vector_type(2))) unsigned int uint2v;

__device__ __forceinline__ unsigned int cvt_pk(float lo, float hi) {
  unsigned int r;
  asm("v_cvt_pk_bf16_f32 %0, %1, %2" : "=v"(r) : "v"(lo), "v"(hi));
  return r;
}
__device__ __forceinline__ unsigned short f2bf(float f) {
  unsigned int u = __float_as_uint(f);
  u += 0x7FFFu + ((u >> 16) & 1u);
  return (unsigned short)(u >> 16);
}
__device__ __forceinline__ float bf2f(unsigned short h) {
  return __uint_as_float(((unsigned int)h) << 16);
}
__device__ __forceinline__ void lgkm0() {
  asm volatile("s_waitcnt lgkmcnt(0)" ::: "memory");
}

// FAT INDEPENDENT WAVES: 256 threads = 4 waves; wave w owns kv-quarter
// [w*256,+256) and processes ALL 64 q-rows (4 subtiles of 16). Each wave
// stages its own K/V chunks into PRIVATE LDS buffers -> ZERO barriers in
// the sweep; staging + A prefetched a full chunk (~2000cy) ahead with
// counted vmcnt that no barrier ever drains. kf/vf loaded once per chunk,
// shared across 4 subtiles. Ps is wave-private by columns (64x512B).
// LDS = 160KB exactly (Ps 128K + 4x8K KV); merge epilogue via overlays.
// SWAPPED QK^T: mfma(A=K,B=Q) -> lane (lg,lm): q=subtile*16+lm,
// kv=sub*16+lg*4+j. All fragment/swizzle formulas from R6/R9/R11 (proven).
__global__ __launch_bounds__(256, 1)
void attn_fused(const float* __restrict__ Q, const float* __restrict__ K,
                const float* __restrict__ V, const int* __restrict__ M,
                const float* __restrict__ A, float* __restrict__ Octx,
                float* __restrict__ Ow)
{
  __shared__ __align__(16) unsigned char LDS[163840];   // 160 KB exactly

  const int t  = threadIdx.x;
  const int w  = t >> 6;
  const int l  = t & 63;
  const int lg = l >> 4;
  const int lm = l & 15;

  // XCD clustering: each bh's 16 q-tiles land on ONE XCD (K/V L2-resident)
  const int bid = blockIdx.x;            // 1024 blocks
  const int y   = bid >> 3;
  const int qt  = y & 15;                // 16 q-tiles of 64 rows
  const int bh  = (bid & 7) * 8 + (y >> 4);
  const int b   = bh >> 4;
  const int q0  = qt * 64;
  const int kvq = w * 256;               // this wave's kv quarter

  unsigned char* PsW = LDS + w * 32768;           // [64 q][512B], XOR (lm<<4)
  unsigned char* KsW = LDS + 131072 + w * 8192;   // [32 kv][128B], XOR (row&7)<<4
  unsigned char* VtW = KsW + 4096;                // [64 d][64B],  XOR ((d>>1)&3)<<4

  const float* Qp = Q + (size_t)bh * NSQ * ND;
  const float* Kp = K + (size_t)bh * NSKV * ND;
  const float* Vp = V + (size_t)bh * NSKV * ND;
  const float* Ap = A + (size_t)bh * NSQ * NSKV;
  const int*   Mp = M + (size_t)b  * NSQ * NSKV;

  const float C = 0.18033688011112042f;  // 0.125 * log2(e)

  // Q fragments for all 4 subtiles: lane holds Q[q0+s*16+lm][dc*32+lg*8+e]
  short8 qf[4][2];
  #pragma unroll
  for (int s = 0; s < 4; ++s) {
    const float* qr = Qp + (size_t)(q0 + s * 16 + lm) * ND + lg * 8;
    #pragma unroll
    for (int dc = 0; dc < 2; ++dc) {
      f32x4 x = *(const f32x4*)(qr + dc * 32);
      f32x4 y2 = *(const f32x4*)(qr + dc * 32 + 4);
      uint4v u;
      u[0] = cvt_pk(x[0], x[1]); u[1] = cvt_pk(x[2], x[3]);
      u[2] = cvt_pk(y2[0], y2[1]); u[3] = cvt_pk(y2[2], y2[3]);
      qf[s][dc] = __builtin_bit_cast(short8, u);
    }
  }

  f32x4 ctx[4][4];
  #pragma unroll
  for (int s = 0; s < 4; ++s)
    #pragma unroll
    for (int ds = 0; ds < 4; ++ds) ctx[s][ds] = (f32x4){0.f, 0.f, 0.f, 0.f};
  float sums[4] = {0.f, 0.f, 0.f, 0.f};

  f32x4 sk[8], sv[8];            // staging regs: one 32-kv chunk in flight
  f32x4 aE[4][2], aO[4][2];      // A (mask+scale folded), alternating sets

  // chunk = 32 kv x 64 d = 2048 f32 contiguous; lane l takes f32[l*4 + i*256]
  auto issueStage = [&](int c) {
    const float* kb = Kp + (size_t)(kvq + c * 32) * ND + l * 4;
    const float* vb = Vp + (size_t)(kvq + c * 32) * ND + l * 4;
    #pragma unroll
    for (int i = 0; i < 8; ++i) {
      sk[i] = *(const f32x4*)(kb + i * 256);
      sv[i] = *(const f32x4*)(vb + i * 256);
    }
  };
  // A with mask fold: amc = m ? a*C : -1.8e8 (exp2 underflows to exact 0)
  auto loadAF = [&](int c, f32x4 (*a)[2]) {
    #pragma unroll
    for (int s = 0; s < 4; ++s)
      #pragma unroll
      for (int sub = 0; sub < 2; ++sub) {
        size_t off = (size_t)(q0 + s * 16 + lm) * NSKV + kvq + c * 32 +
                     sub * 16 + lg * 4;
        f32x4 av = *(const f32x4*)(Ap + off);
        int4v mv = *(const int4v*)(Mp + off);
        f32x4 r;
        #pragma unroll
        for (int j = 0; j < 4; ++j) r[j] = mv[j] ? av[j] * C : -1.8e8f;
        a[s][sub] = r;
      }
  };
  auto writeStage = [&]() {      // R6-proven K formula; R9-proven V formula
    #pragma unroll
    for (int i = 0; i < 8; ++i) {
      int f   = l * 4 + i * 256;
      int row = f >> 6;          // kv-local 0..31
      int c0  = f & 63;          // d base (multiple of 4)
      uint2v ku;
      ku[0] = cvt_pk(sk[i][0], sk[i][1]); ku[1] = cvt_pk(sk[i][2], sk[i][3]);
      *(uint2v*)(KsW + row * 128 + ((c0 * 2) ^ ((row & 7) << 4))) = ku;
      #pragma unroll
      for (int j = 0; j < 4; ++j) {
        int d = c0 + j;
        *(unsigned short*)(VtW + d * 64 + ((row * 2) ^ (((d >> 1) & 3) << 4))) =
            f2bf(sv[i][j]);
      }
    }
  };

  auto body = [&](int c, f32x4 (*aCur)[2], f32x4 (*aNext)[2], int cn) {
    writeStage();                // counted vmcnt on sk/sv (issued last chunk)
    issueStage(cn);              // next chunk loads -> in flight across body
    loadAF(cn, aNext);           // next chunk's A -> in flight across body
    lgkm0();                     // own-wave staging visible (vm stays live)
    __builtin_amdgcn_sched_barrier(0);

    const int ksw = (lm & 7) << 4;
    const int vsw = ((lm >> 1) & 3) << 4;
    short8 kf[4];
    #pragma unroll
    for (int sub = 0; sub < 2; ++sub)
      #pragma unroll
      for (int dc = 0; dc < 2; ++dc)
        kf[sub * 2 + dc] = *(const short8*)(
            KsW + (sub * 16 + lm) * 128 + ((dc * 64 + lg * 16) ^ ksw));
    short8 vf[4];
    #pragma unroll
    for (int ds = 0; ds < 4; ++ds)
      vf[ds] = *(const short8*)(VtW + (ds * 16 + lm) * 64 + ((lg * 16) ^ vsw));

    __builtin_amdgcn_s_setprio(1);
    // QK^T + exp -> Ps, for all 4 q-subtiles (kf shared across subtiles)
    #pragma unroll
    for (int s = 0; s < 4; ++s) {
      #pragma unroll
      for (int sub = 0; sub < 2; ++sub) {
        f32x4 acc = (f32x4){0.f, 0.f, 0.f, 0.f};
        #pragma unroll
        for (int dc = 0; dc < 2; ++dc)
          acc = __builtin_amdgcn_mfma_f32_16x16x32_bf16(kf[sub * 2 + dc],
                                                        qf[s][dc], acc, 0, 0, 0);
        float pe[4];
        #pragma unroll
        for (int j = 0; j < 4; ++j) {
          pe[j] = exp2f(fmaf(acc[j], C, aCur[s][sub][j]));  // masked -> 0
          sums[s] += pe[j];
        }
        uint2v u2;
        u2[0] = cvt_pk(pe[0], pe[1]); u2[1] = cvt_pk(pe[2], pe[3]);
        *(uint2v*)(PsW + (s * 16 + lm) * 512 +
                   (((c * 32 + sub * 16 + lg * 4) * 2) ^ (lm << 4))) = u2;
      }
    }
    // own-wave Ps RAW fence (rule #18)
    lgkm0();
    __builtin_amdgcn_sched_barrier(0);
    // PV: pf = P[q=s*16+lm][kv_local c*32+lg*8..+7]; same k-map as vf
    #pragma unroll
    for (int s = 0; s < 4; ++s) {
      short8 pf = *(const short8*)(PsW + (s * 16 + lm) * 512 +
                                   (((c * 32 + lg * 8) * 2) ^ (lm << 4)));
      #pragma unroll
      for (int ds = 0; ds < 4; ++ds)
        ctx[s][ds] = __builtin_amdgcn_mfma_f32_16x16x32_bf16(pf, vf[ds],
                                                             ctx[s][ds], 0, 0, 0);
    }
    __builtin_amdgcn_s_setprio(0);
  };

  // ---- barrier-free sweep: 8 chunks of 32 kv in this wave's quarter ----
  issueStage(0);
  loadAF(0, aE);
  for (int c = 0; c < 8; c += 2) {
    body(c,     aE, aO, (c + 1 > 7) ? 7 : c + 1);
    body(c + 1, aO, aE, (c + 2 > 7) ? 7 : c + 2);
  }

  // ---- reduce sums across lg (full quarter-sum for q=s*16+lm) ----
  #pragma unroll
  for (int s = 0; s < 4; ++s) {
    sums[s] += __shfl_xor(sums[s], 16);
    sums[s] += __shfl_xor(sums[s], 32);
  }
  __syncthreads();               // all sweep LDS use complete block-wide

  float (*SumS)[4] = (float(*)[4])(LDS + 131072);          // 64 x 4 overlay
  float (*B1)[64]  = (float(*)[64])(LDS + 131072 + 1024);  // 64 x 64 overlay
  if (lg == 0) {
    #pragma unroll
    for (int s = 0; s < 4; ++s) SumS[s * 16 + lm][w] = sums[s];
  }
  __syncthreads();               // SumS visible

  // ---- weights out: each wave stores its own column-quarter, all 64 rows ----
  float* Owp = Ow + (size_t)bh * NSQ * NSKV + (size_t)q0 * NSKV + kvq;
  for (int r = 0; r < 64; ++r) {
    float rr = 1.0f / (SumS[r][0] + SumS[r][1] + SumS[r][2] + SumS[r][3]);
    short4v p = *(const short4v*)(PsW + r * 512 + ((l * 8) ^ ((r & 15) << 4)));
    f32x4 o;
    o[0] = bf2f((unsigned short)p[0]) * rr;
    o[1] = bf2f((unsigned short)p[1]) * rr;
    o[2] = bf2f((unsigned short)p[2]) * rr;
    o[3] = bf2f((unsigned short)p[3]) * rr;
    *(f32x4*)&Owp[(size_t)r * NSKV + l * 4] = o;
  }

  // ---- ctx merge: waves 1..3 sequentially through B1; wave 0 accumulates ----
  for (int k = 1; k < 4; ++k) {
    __syncthreads();
    if (w == k) {
      #pragma unroll
      for (int s = 0; s < 4; ++s)
        #pragma unroll
        for (int ds = 0; ds < 4; ++ds)
          #pragma unroll
          for (int j = 0; j < 4; ++j)
            B1[s * 16 + lg * 4 + j][ds * 16 + lm] = ctx[s][ds][j];
    }
    __syncthreads();
    if (w == 0) {
      #pragma unroll
      for (int s = 0; s < 4; ++s)
        #pragma unroll
        for (int ds = 0; ds < 4; ++ds)
          #pragma unroll
          for (int j = 0; j < 4; ++j)
            ctx[s][ds][j] += B1[s * 16 + lg * 4 + j][ds * 16 + lm];
    }
  }

  if (w == 0) {
    #pragma unroll
    for (int s = 0; s < 4; ++s)
      #pragma unroll
      for (int j = 0; j < 4; ++j) {
        int q = s * 16 + lg * 4 + j;
        float rc = 1.0f / (SumS[q][0] + SumS[q][1] + SumS[q][2] + SumS[q][3]);
        #pragma unroll
        for (int ds = 0; ds < 4; ++ds)
          Octx[((size_t)bh * NSQ + q0 + q) * ND + ds * 16 + lm] =
              ctx[s][ds][j] * rc;
      }
  }
}

extern "C" void kernel_launch(void* const* d_in, const int* in_sizes, int n_in,
                              void* d_out, int out_size, void* d_ws, size_t ws_size,
                              hipStream_t stream) {
  const float* Q = (const float*)d_in[0];
  const float* K = (const float*)d_in[1];
  const float* V = (const float*)d_in[2];
  const int*   M = (const int*)d_in[3];
  const float* A = (const float*)d_in[4];
  float* ctx = (float*)d_out;
  float* wts = ctx + (size_t)NB * NH * NSQ * ND;  // outputs: (context, weights)
  dim3 grid(NB * NH * (NSQ / 64));                // 1024 blocks
  attn_fused<<<grid, dim3(256), 0, stream>>>(Q, K, V, M, A, ctx, wts);
}

// Round 17
// 183.889 us; speedup vs baseline: 1.2565x; 1.2565x over previous
//
#include <hip/hip_runtime.h>

#define NB 4
#define NH 16
#define NSQ 1024
#define NSKV 1024
#define ND 64

typedef __attribute__((ext_vector_type(8))) short short8;
typedef __attribute__((ext_vector_type(4))) float f32x4;
typedef __attribute__((ext_vector_type(4))) int int4v;
typedef __attribute__((ext_vector_type(4))) unsigned int uint4v;
typedef __attribute__((ext_vector_type(2))) unsigned int uint2v;

__device__ __forceinline__ unsigned int cvt_pk(float lo, float hi) {
  unsigned int r;
  asm("v_cvt_pk_bf16_f32 %0, %1, %2" : "=v"(r) : "v"(lo), "v"(hi));
  return r;
}
__device__ __forceinline__ float bf2f(unsigned short h) {
  return __uint_as_float(((unsigned int)h) << 16);
}
__device__ __forceinline__ void bar() { __builtin_amdgcn_s_barrier(); }
__device__ __forceinline__ void lgkm0() {
  asm volatile("s_waitcnt lgkmcnt(0)" ::: "memory");
}
// gfx950 cross-lane half-swaps (pure VALU, no LDS pipe):
// P32: dst.lanes[32:63] <-> src.lanes[0:31]
// P16: dst.lanes[16:31]<->src.lanes[0:15]; dst.lanes[48:63]<->src.lanes[32:47]
__device__ __forceinline__ void pl32(unsigned& a, unsigned& b) {
  asm("v_permlane32_swap_b32 %0, %1" : "+v"(a), "+v"(b));
}
__device__ __forceinline__ void pl16(unsigned& a, unsigned& b) {
  asm("v_permlane16_swap_b32 %0, %1" : "+v"(a), "+v"(b));
}

// R11 champion (phase-staggered halves) with LDS data-movement moved to the
// VALU via permlane butterflies:
// (1) V staging: 4x4 in-register transpose across lanes {l,l+16,l+32,l+48}
//     (2xP32 + 2xP16) -> ONE b64 LDS write replaces the 4-u16 scatter storm.
// (2) PV A-fragment: the P-pairs each lane holds after QK^T are permlane-
//     redistributed (2xP32 + 2xP16) into pf directly -> the Ps read-back and
//     the mid-compute lgkm fence are DELETED (Ps writes stay, fire-and-forget
//     for the weights epilogue).
// LDS wave-ops per barrier interval drop ~30%; all other formulas = R11.
__global__ __launch_bounds__(512, 2)
void attn_fused(const float* __restrict__ Q, const float* __restrict__ K,
                const float* __restrict__ V, const int* __restrict__ M,
                const float* __restrict__ A, float* __restrict__ Octx,
                float* __restrict__ Ow)
{
  __shared__ unsigned short Ps[64 * 1024];       // 128 KB, rows 2048B, XOR (lm<<4)
  __shared__ __align__(16) unsigned char Stg[18432]; // staging; CtxS overlay post-sweep
  __shared__ float SumS[64][2];

  const int t  = threadIdx.x;
  const int w  = t >> 6;
  const int l  = t & 63;
  const int lg = l >> 4;       // 0..3
  const int lm = l & 15;
  const int p  = w & 3;        // q-row pair id
  const int h  = w >> 2;       // kv half
  const int g  = p * 64 + l;   // gang lane within half (0..255)

  // XCD clustering: each bh's 16 q-tiles land on ONE XCD (K/V L2-resident)
  const int bid = blockIdx.x;            // 1024 blocks
  const int y   = bid >> 3;
  const int qt  = y & 15;                // 16 q-tiles of 64 rows
  const int bh  = (bid & 7) * 8 + (y >> 4);
  const int b   = bh >> 4;
  const int q0  = qt * 64;
  const int kvb = h * 512;

  unsigned char* KsB = Stg + h * 4096;           // [32 rows][128B], XOR (row&7)<<4
  unsigned char* VtB = Stg + 8192 + h * 5120;    // [64 d-rows][80B], XOR ((d>>2)&3)<<4

  const float* Qp = Q + (size_t)bh * NSQ * ND;
  const float* Kp = K + (size_t)bh * NSKV * ND;
  const float* Vp = V + (size_t)bh * NSKV * ND;
  const float* Ap = A + (size_t)bh * NSQ * NSKV;
  const int*   Mp = M + (size_t)b  * NSQ * NSKV;

  const float C = 0.18033688011112042f;  // 0.125 * log2(e)

  // Q fragment (B operand of QK^T): lane holds Q[q0+p*16+lm][dc*32+lg*8+e]
  short8 qf[2];
  {
    const float* qr = Qp + (size_t)(q0 + p * 16 + lm) * ND + lg * 8;
    #pragma unroll
    for (int dc = 0; dc < 2; ++dc) {
      f32x4 x = *(const f32x4*)(qr + dc * 32);
      f32x4 y2 = *(const f32x4*)(qr + dc * 32 + 4);
      uint4v u;
      u[0] = cvt_pk(x[0], x[1]); u[1] = cvt_pk(x[2], x[3]);
      u[2] = cvt_pk(y2[0], y2[1]); u[3] = cvt_pk(y2[2], y2[3]);
      qf[dc] = __builtin_bit_cast(short8, u);
    }
  }

  f32x4 ctx[4];
  #pragma unroll
  for (int i = 0; i < 4; ++i) ctx[i] = (f32x4){0.f, 0.f, 0.f, 0.f};
  float sum = 0.f;

  f32x4 sk[2], sv[2];                        // staging regs (one chunk in flight)
  f32x4 aA[2], aB[2];  int4v mA[2], mB[2];   // A/M alternating buffers

  // chunk = 32 kv x 64 d = 2048 f32 contiguous; gang lane g takes g*4 + i*1024
  auto issueStage = [&](int c) {
    int kv0 = kvb + c * 32;
    const float* kb = Kp + (size_t)kv0 * ND + g * 4;
    const float* vb = Vp + (size_t)kv0 * ND + g * 4;
    sk[0] = *(const f32x4*)kb;       sk[1] = *(const f32x4*)(kb + 1024);
    sv[0] = *(const f32x4*)vb;       sv[1] = *(const f32x4*)(vb + 1024);
  };
  auto loadAM = [&](int c, f32x4* a, int4v* m) {
    int kv0 = kvb + c * 32;
    #pragma unroll
    for (int sub = 0; sub < 2; ++sub) {
      size_t off = (size_t)(q0 + p * 16 + lm) * NSKV + kv0 + sub * 16 + lg * 4;
      a[sub] = *(const f32x4*)(Ap + off);
      m[sub] = *(const int4v*)(Mp + off);
    }
  };
  auto writeStage = [&]() {
    // K: unchanged (2 clean b64 writes, R11 formula)
    #pragma unroll
    for (int i = 0; i < 2; ++i) {
      int f = g * 4 + i * 1024;
      int row = f >> 6;
      int cb  = (f & 63) * 2;
      uint2v u;
      u[0] = cvt_pk(sk[i][0], sk[i][1]);
      u[1] = cvt_pk(sk[i][2], sk[i][3]);
      *(uint2v*)(KsB + row * 128 + (cb ^ ((row & 7) << 4))) = u;
    }
    // V: in-register 4x4 transpose (Eklundh butterfly) across lanes
    // {l, l+16, l+32, l+48}, then ONE b64 write per iteration.
    // Pre: lane (x=l&15, m=l>>4) holds sv[i][j] = V[4p+16i+m][4x+j].
    // Post: reg j = V[4p+16i+j][4x+m]  -> d = 4x+m, kvbase = 4p+16i.
    #pragma unroll
    for (int i = 0; i < 2; ++i) {
      unsigned r0 = __float_as_uint(sv[i][0]);
      unsigned r1 = __float_as_uint(sv[i][1]);
      unsigned r2 = __float_as_uint(sv[i][2]);
      unsigned r3 = __float_as_uint(sv[i][3]);
      pl32(r0, r2); pl32(r1, r3);    // stage A: swap on bit1(m)!=bit1(j)
      pl16(r0, r1); pl16(r2, r3);    // stage B: swap on bit0(m)!=bit0(j)
      int d = 4 * (l & 15) + (l >> 4);
      int kvbase = 4 * p + 16 * i;
      uint2v vu;
      vu[0] = cvt_pk(__uint_as_float(r0), __uint_as_float(r1));
      vu[1] = cvt_pk(__uint_as_float(r2), __uint_as_float(r3));
      *(uint2v*)(VtB + d * 80 + ((kvbase * 2) ^ (((d >> 2) & 3) << 4))) = vu;
    }
  };

  auto compute = [&](int c, const f32x4* a, const int4v* m) {
    int kv0 = kvb + c * 32;
    const int ksw = (lm & 7) << 4;
    const int vsw = ((lm >> 2) & 3) << 4;
    short8 kf[4];
    #pragma unroll
    for (int sub = 0; sub < 2; ++sub)
      #pragma unroll
      for (int dc = 0; dc < 2; ++dc)
        kf[sub * 2 + dc] = *(const short8*)(
            KsB + (sub * 16 + lm) * 128 + ((dc * 64 + lg * 16) ^ ksw));
    short8 vf[4];
    #pragma unroll
    for (int ds = 0; ds < 4; ++ds)
      vf[ds] = *(const short8*)(VtB + (ds * 16 + lm) * 80 + ((lg * 16) ^ vsw));

    __builtin_amdgcn_s_setprio(1);
    // QK^T (A=K,B=Q): acc[j] = logit(q=lm, kv=kv0+sub*16+lg*4+j)
    unsigned s0, s1, s2, s3;
    {
      f32x4 acc = (f32x4){0.f, 0.f, 0.f, 0.f};
      acc = __builtin_amdgcn_mfma_f32_16x16x32_bf16(kf[0], qf[0], acc, 0, 0, 0);
      acc = __builtin_amdgcn_mfma_f32_16x16x32_bf16(kf[1], qf[1], acc, 0, 0, 0);
      float pe[4];
      #pragma unroll
      for (int j = 0; j < 4; ++j) {
        float amc = m[0][j] ? a[0][j] * C : -1.8e8f;
        pe[j] = exp2f(fmaf(acc[j], C, amc));   // masked -> exact 0
        sum += pe[j];
      }
      s0 = cvt_pk(pe[0], pe[1]); s1 = cvt_pk(pe[2], pe[3]);
      uint2v u2; u2[0] = s0; u2[1] = s1;
      *(uint2v*)((char*)Ps + (p * 16 + lm) * 2048 +
                 (((kv0 + lg * 4) * 2) ^ (lm << 4))) = u2;
    }
    {
      f32x4 acc = (f32x4){0.f, 0.f, 0.f, 0.f};
      acc = __builtin_amdgcn_mfma_f32_16x16x32_bf16(kf[2], qf[0], acc, 0, 0, 0);
      acc = __builtin_amdgcn_mfma_f32_16x16x32_bf16(kf[3], qf[1], acc, 0, 0, 0);
      float pe[4];
      #pragma unroll
      for (int j = 0; j < 4; ++j) {
        float amc = m[1][j] ? a[1][j] * C : -1.8e8f;
        pe[j] = exp2f(fmaf(acc[j], C, amc));
        sum += pe[j];
      }
      s2 = cvt_pk(pe[0], pe[1]); s3 = cvt_pk(pe[2], pe[3]);
      uint2v u2; u2[0] = s2; u2[1] = s3;
      *(uint2v*)((char*)Ps + (p * 16 + lm) * 2048 +
                 (((kv0 + 16 + lg * 4) * 2) ^ (lm << 4))) = u2;
    }
    // pf via permlane redistribution (replaces Ps read-back + lgkm fence):
    // source: member g holds P-pairs {2g, 2g+1, 8+2g, 8+2g+1} (pair = 2 kv);
    // target: member m needs pairs {4m..4m+3} = kv {8m..8m+7}.
    pl32(s0, s2); pl32(s1, s3);
    pl16(s0, s2); pl16(s1, s3);
    uint4v pu; pu[0] = s0; pu[1] = s1; pu[2] = s2; pu[3] = s3;
    short8 pf = __builtin_bit_cast(short8, pu);
    #pragma unroll
    for (int ds = 0; ds < 4; ++ds)
      ctx[ds] = __builtin_amdgcn_mfma_f32_16x16x32_bf16(pf, vf[ds], ctx[ds], 0, 0, 0);
    __builtin_amdgcn_s_setprio(0);
  };

  // ---- prologue: phase offset between halves ----
  issueStage(0);
  loadAM(0, aA, mA);
  if (h == 1) {
    writeStage();                 // vmcnt wait on chunk0 loads
    issueStage(1);                // chunk1 in flight
    loadAM(1, aB, mB);
  }
  lgkm0(); bar();

  // ---- staggered sweep: 16 chunks per half ----
  for (int c = 0; c < 16; c += 2) {
    int n1 = (c + 1 > 15) ? 15 : c + 1;
    int n2 = (c + 2 > 15) ? 15 : c + 2;
    int n3 = (c + 3 > 15) ? 15 : c + 3;
    if (h == 0) { writeStage(); issueStage(n1); loadAM(n1, aB, mB); }
    else        { compute(c, aA, mA); }
    lgkm0(); bar();
    if (h == 0) { compute(c, aA, mA); }
    else        { writeStage(); issueStage(n2); loadAM(n2, aA, mA); }
    lgkm0(); bar();
    if (h == 0) { writeStage(); issueStage(n2); loadAM(n2, aA, mA); }
    else        { compute(c + 1, aB, mB); }
    lgkm0(); bar();
    if (h == 0) { compute(c + 1, aB, mB); }
    else        { writeStage(); issueStage(n3); loadAM(n3, aB, mB); }
    lgkm0(); bar();
  }

  // ---- merge halves (R11-verbatim epilogue) ----
  sum += __shfl_xor(sum, 16);
  sum += __shfl_xor(sum, 32);
  if (lg == 0) SumS[p * 16 + lm][h] = sum;
  lgkm0(); bar();                        // all sweeps + Ps writes drained

  float (*CtxS)[16][64] = (float(*)[16][64])Stg;   // overlay staging area
  if (h == 1) {
    #pragma unroll
    for (int ds = 0; ds < 4; ++ds)
      #pragma unroll
      for (int j = 0; j < 4; ++j)
        CtxS[p][lg * 4 + j][ds * 16 + lm] = ctx[ds][j];
  }
  lgkm0(); bar();

  if (h == 0) {
    float rcpj[4];
    #pragma unroll
    for (int j = 0; j < 4; ++j) {
      int r = p * 16 + lg * 4 + j;
      rcpj[j] = 1.0f / (SumS[r][0] + SumS[r][1]);
    }
    #pragma unroll
    for (int ds = 0; ds < 4; ++ds)
      #pragma unroll
      for (int j = 0; j < 4; ++j)
        Octx[((size_t)bh * NSQ + q0 + p * 16 + lg * 4 + j) * ND + ds * 16 + lm] =
            (ctx[ds][j] + CtxS[p][lg * 4 + j][ds * 16 + lm]) * rcpj[j];
  }

  // ---- weights out: wave writes its own 16 rows x its 512-kv half ----
  float* Owp = Ow + (size_t)bh * NSQ * NSKV + (size_t)(q0 + p * 16) * NSKV;
  for (int r = 0; r < 16; ++r) {
    float rr = 1.0f / (SumS[p * 16 + r][0] + SumS[p * 16 + r][1]);
    int kv = kvb + l * 8;
    short8 pv = *(const short8*)((char*)Ps + (p * 16 + r) * 2048 +
                                 ((kv * 2) ^ (r << 4)));
    f32x4 o1, o2;
    o1[0] = bf2f((unsigned short)pv[0]) * rr;
    o1[1] = bf2f((unsigned short)pv[1]) * rr;
    o1[2] = bf2f((unsigned short)pv[2]) * rr;
    o1[3] = bf2f((unsigned short)pv[3]) * rr;
    o2[0] = bf2f((unsigned short)pv[4]) * rr;
    o2[1] = bf2f((unsigned short)pv[5]) * rr;
    o2[2] = bf2f((unsigned short)pv[6]) * rr;
    o2[3] = bf2f((unsigned short)pv[7]) * rr;
    *(f32x4*)&Owp[(size_t)r * NSKV + kv]     = o1;
    *(f32x4*)&Owp[(size_t)r * NSKV + kv + 4] = o2;
  }
}

extern "C" void kernel_launch(void* const* d_in, const int* in_sizes, int n_in,
                              void* d_out, int out_size, void* d_ws, size_t ws_size,
                              hipStream_t stream) {
  const float* Q = (const float*)d_in[0];
  const float* K = (const float*)d_in[1];
  const float* V = (const float*)d_in[2];
  const int*   M = (const int*)d_in[3];
  const float* A = (const float*)d_in[4];
  float* ctx = (float*)d_out;
  float* wts = ctx + (size_t)NB * NH * NSQ * ND;  // outputs: (context, weights)
  dim3 grid(NB * NH * (NSQ / 64));                // 1024 blocks
  attn_fused<<<grid, dim3(512), 0, stream>>>(Q, K, V, M, A, ctx, wts);
}

// Round 18
// 183.672 us; speedup vs baseline: 1.2580x; 1.0012x over previous
//
#include <hip/hip_runtime.h>

#define NB 4
#define NH 16
#define NSQ 1024
#define NSKV 1024
#define ND 64

typedef __attribute__((ext_vector_type(8))) short short8;
typedef __attribute__((ext_vector_type(4))) float f32x4;
typedef __attribute__((ext_vector_type(4))) int int4v;
typedef __attribute__((ext_vector_type(4))) unsigned int uint4v;
typedef __attribute__((ext_vector_type(2))) unsigned int uint2v;

__device__ __forceinline__ unsigned int cvt_pk(float lo, float hi) {
  unsigned int r;
  asm("v_cvt_pk_bf16_f32 %0, %1, %2" : "=v"(r) : "v"(lo), "v"(hi));
  return r;
}
__device__ __forceinline__ float bf2f(unsigned short h) {
  return __uint_as_float(((unsigned int)h) << 16);
}
__device__ __forceinline__ void bar() { __builtin_amdgcn_s_barrier(); }
__device__ __forceinline__ void lgkm0() {
  asm volatile("s_waitcnt lgkmcnt(0)" ::: "memory");
}
// gfx950 cross-lane half-swaps (pure VALU, no LDS pipe) — R17-verified.
__device__ __forceinline__ void pl32(unsigned& a, unsigned& b) {
  asm("v_permlane32_swap_b32 %0, %1" : "+v"(a), "+v"(b));
}
__device__ __forceinline__ void pl16(unsigned& a, unsigned& b) {
  asm("v_permlane16_swap_b32 %0, %1" : "+v"(a), "+v"(b));
}

// R17 champion + BK=64 CHUNKS: barriers per kv HALVED (16 sweep barriers vs
// 32). LDS = 160KB exactly: Ps 128K + per-half {K [64][128B], V [64][128B]}
// (SumS/CtxS overlaid on staging post-sweep). V staged via R17's permlane
// in-register 4x4 transpose (b64 writes); pf via R17's permlane
// redistribution (no Ps read-back, no mid-compute fence). Mask folded at
// A-load (R14-proven formula) so A/M register cost stays flat.
// 512 threads = 8 waves: p=w&3 -> q-rows [q0+p*16,+16); h=w>>2 -> kv half;
// halves run OPPOSITE stage/compute phases (R11 stagger).
__global__ __launch_bounds__(512, 2)
void attn_fused(const float* __restrict__ Q, const float* __restrict__ K,
                const float* __restrict__ V, const int* __restrict__ M,
                const float* __restrict__ A, float* __restrict__ Octx,
                float* __restrict__ Ow)
{
  __shared__ unsigned short Ps[64 * 1024];           // 128 KB, rows 2048B, XOR (lm<<4)
  __shared__ __align__(16) unsigned char Stg[32768]; // staging; SumS/CtxS overlay

  const int t  = threadIdx.x;
  const int w  = t >> 6;
  const int l  = t & 63;
  const int lg = l >> 4;       // 0..3
  const int lm = l & 15;
  const int p  = w & 3;        // q-row pair id
  const int h  = w >> 2;       // kv half
  const int g  = p * 64 + l;   // gang lane within half (0..255)

  // XCD clustering: each bh's 16 q-tiles land on ONE XCD (K/V L2-resident)
  const int bid = blockIdx.x;            // 1024 blocks
  const int y   = bid >> 3;
  const int qt  = y & 15;                // 16 q-tiles of 64 rows
  const int bh  = (bid & 7) * 8 + (y >> 4);
  const int b   = bh >> 4;
  const int q0  = qt * 64;
  const int kvb = h * 512;

  unsigned char* KsB = Stg + h * 16384;          // [64 rows][128B], XOR (row&7)<<4
  unsigned char* VtB = KsB + 8192;               // [64 d][128B],   XOR (d&7)<<4

  const float* Qp = Q + (size_t)bh * NSQ * ND;
  const float* Kp = K + (size_t)bh * NSKV * ND;
  const float* Vp = V + (size_t)bh * NSKV * ND;
  const float* Ap = A + (size_t)bh * NSQ * NSKV;
  const int*   Mp = M + (size_t)b  * NSQ * NSKV;

  const float C = 0.18033688011112042f;  // 0.125 * log2(e)

  // Q fragment (B operand of QK^T): lane holds Q[q0+p*16+lm][dc*32+lg*8+e]
  short8 qf[2];
  {
    const float* qr = Qp + (size_t)(q0 + p * 16 + lm) * ND + lg * 8;
    #pragma unroll
    for (int dc = 0; dc < 2; ++dc) {
      f32x4 x = *(const f32x4*)(qr + dc * 32);
      f32x4 y2 = *(const f32x4*)(qr + dc * 32 + 4);
      uint4v u;
      u[0] = cvt_pk(x[0], x[1]); u[1] = cvt_pk(x[2], x[3]);
      u[2] = cvt_pk(y2[0], y2[1]); u[3] = cvt_pk(y2[2], y2[3]);
      qf[dc] = __builtin_bit_cast(short8, u);
    }
  }

  f32x4 ctx[4];
  #pragma unroll
  for (int i = 0; i < 4; ++i) ctx[i] = (f32x4){0.f, 0.f, 0.f, 0.f};
  float sum = 0.f;

  f32x4 sk[4], sv[4];            // staging regs: one 64-kv chunk in flight
  f32x4 aA[4], aB[4];            // A (mask+scale folded), alternating buffers

  // chunk = 64 kv x 64 d = 4096 f32 contiguous; gang lane g: g*4 + i*1024
  auto issueStage = [&](int c) {
    int kv0 = kvb + c * 64;
    const float* kb = Kp + (size_t)kv0 * ND + g * 4;
    const float* vb = Vp + (size_t)kv0 * ND + g * 4;
    #pragma unroll
    for (int i = 0; i < 4; ++i) {
      sk[i] = *(const f32x4*)(kb + i * 1024);
      sv[i] = *(const f32x4*)(vb + i * 1024);
    }
  };
  // A with mask fold: r[j] = m ? a*C : -1.8e8 (exp2 underflows to exact 0)
  auto loadAF = [&](int c, f32x4* a) {
    int kv0 = kvb + c * 64;
    #pragma unroll
    for (int sub = 0; sub < 4; ++sub) {
      size_t off = (size_t)(q0 + p * 16 + lm) * NSKV + kv0 + sub * 16 + lg * 4;
      f32x4 av = *(const f32x4*)(Ap + off);
      int4v mv = *(const int4v*)(Mp + off);
      f32x4 r;
      #pragma unroll
      for (int j = 0; j < 4; ++j) r[j] = mv[j] ? av[j] * C : -1.8e8f;
      a[sub] = r;
    }
  };
  auto writeStage = [&]() {
    #pragma unroll
    for (int i = 0; i < 4; ++i) {
      int f = g * 4 + i * 1024;
      int row = f >> 6;            // kv-local 0..63
      int cb  = (f & 63) * 2;      // byte col in 128B row (8B-aligned)
      uint2v u;
      u[0] = cvt_pk(sk[i][0], sk[i][1]);
      u[1] = cvt_pk(sk[i][2], sk[i][3]);
      *(uint2v*)(KsB + row * 128 + (cb ^ ((row & 7) << 4))) = u;
      // V: in-register 4x4 transpose (R17-verified butterfly) across lanes
      // {l, l+16, l+32, l+48}; post: reg j = V[kvbase+j][4x+m], one b64 write.
      unsigned r0 = __float_as_uint(sv[i][0]);
      unsigned r1 = __float_as_uint(sv[i][1]);
      unsigned r2 = __float_as_uint(sv[i][2]);
      unsigned r3 = __float_as_uint(sv[i][3]);
      pl32(r0, r2); pl32(r1, r3);
      pl16(r0, r1); pl16(r2, r3);
      int d = 4 * (l & 15) + (l >> 4);
      int kvbase = 4 * p + 16 * i;
      uint2v vu;
      vu[0] = cvt_pk(__uint_as_float(r0), __uint_as_float(r1));
      vu[1] = cvt_pk(__uint_as_float(r2), __uint_as_float(r3));
      *(uint2v*)(VtB + d * 128 + ((kvbase * 2) ^ ((d & 7) << 4))) = vu;
    }
  };

  auto compute = [&](int c, const f32x4* a) {
    int kv0 = kvb + c * 64;
    const int ksw = (lm & 7) << 4;
    __builtin_amdgcn_s_setprio(1);
    #pragma unroll
    for (int kh = 0; kh < 2; ++kh) {
      // fragments for this 32-kv half of the chunk (bounded live registers)
      short8 kf[4];
      #pragma unroll
      for (int sj = 0; sj < 2; ++sj)
        #pragma unroll
        for (int dc = 0; dc < 2; ++dc)
          kf[sj * 2 + dc] = *(const short8*)(
              KsB + ((kh * 2 + sj) * 16 + lm) * 128 + ((dc * 64 + lg * 16) ^ ksw));
      short8 vf[4];
      #pragma unroll
      for (int ds = 0; ds < 4; ++ds)
        vf[ds] = *(const short8*)(
            VtB + (ds * 16 + lm) * 128 + ((kh * 64 + lg * 16) ^ ksw));

      unsigned s0, s1, s2, s3;
      {
        const int sub = kh * 2;
        f32x4 acc = (f32x4){0.f, 0.f, 0.f, 0.f};
        acc = __builtin_amdgcn_mfma_f32_16x16x32_bf16(kf[0], qf[0], acc, 0, 0, 0);
        acc = __builtin_amdgcn_mfma_f32_16x16x32_bf16(kf[1], qf[1], acc, 0, 0, 0);
        float pe[4];
        #pragma unroll
        for (int j = 0; j < 4; ++j) {
          pe[j] = exp2f(fmaf(acc[j], C, a[sub][j]));   // masked -> exact 0
          sum += pe[j];
        }
        s0 = cvt_pk(pe[0], pe[1]); s1 = cvt_pk(pe[2], pe[3]);
        uint2v u2; u2[0] = s0; u2[1] = s1;
        *(uint2v*)((char*)Ps + (p * 16 + lm) * 2048 +
                   (((kv0 + kh * 32 + lg * 4) * 2) ^ (lm << 4))) = u2;
      }
      {
        const int sub = kh * 2 + 1;
        f32x4 acc = (f32x4){0.f, 0.f, 0.f, 0.f};
        acc = __builtin_amdgcn_mfma_f32_16x16x32_bf16(kf[2], qf[0], acc, 0, 0, 0);
        acc = __builtin_amdgcn_mfma_f32_16x16x32_bf16(kf[3], qf[1], acc, 0, 0, 0);
        float pe[4];
        #pragma unroll
        for (int j = 0; j < 4; ++j) {
          pe[j] = exp2f(fmaf(acc[j], C, a[sub][j]));
          sum += pe[j];
        }
        s2 = cvt_pk(pe[0], pe[1]); s3 = cvt_pk(pe[2], pe[3]);
        uint2v u2; u2[0] = s2; u2[1] = s3;
        *(uint2v*)((char*)Ps + (p * 16 + lm) * 2048 +
                   (((kv0 + kh * 32 + 16 + lg * 4) * 2) ^ (lm << 4))) = u2;
      }
      // pf via permlane redistribution (R17-verified; no Ps read-back)
      pl32(s0, s2); pl32(s1, s3);
      pl16(s0, s2); pl16(s1, s3);
      uint4v pu; pu[0] = s0; pu[1] = s1; pu[2] = s2; pu[3] = s3;
      short8 pf = __builtin_bit_cast(short8, pu);
      #pragma unroll
      for (int ds = 0; ds < 4; ++ds)
        ctx[ds] = __builtin_amdgcn_mfma_f32_16x16x32_bf16(pf, vf[ds], ctx[ds], 0, 0, 0);
    }
    __builtin_amdgcn_s_setprio(0);
  };

  // ---- prologue: phase offset between halves ----
  issueStage(0);
  loadAF(0, aA);
  if (h == 1) {
    writeStage();                 // vmcnt wait on chunk0 loads
    issueStage(1);                // chunk1 in flight
    loadAF(1, aB);
  }
  lgkm0(); bar();

  // ---- staggered sweep: 8 chunks of 64 kv per half (16 barriers) ----
  for (int c = 0; c < 8; c += 2) {
    int n1 = (c + 1 > 7) ? 7 : c + 1;
    int n2 = (c + 2 > 7) ? 7 : c + 2;
    int n3 = (c + 3 > 7) ? 7 : c + 3;
    if (h == 0) { writeStage(); issueStage(n1); loadAF(n1, aB); }
    else        { compute(c, aA); }
    lgkm0(); bar();
    if (h == 0) { compute(c, aA); }
    else        { writeStage(); issueStage(n2); loadAF(n2, aA); }
    lgkm0(); bar();
    if (h == 0) { writeStage(); issueStage(n2); loadAF(n2, aA); }
    else        { compute(c + 1, aB); }
    lgkm0(); bar();
    if (h == 0) { compute(c + 1, aB); }
    else        { writeStage(); issueStage(n3); loadAF(n3, aB); }
    lgkm0(); bar();
  }

  // ---- merge halves (staging regions dead after this barrier) ----
  sum += __shfl_xor(sum, 16);
  sum += __shfl_xor(sum, 32);
  __syncthreads();

  float (*SumS)[2]     = (float(*)[2])Stg;                  // 64x2 overlay
  float (*CtxS)[16][64] = (float(*)[16][64])(Stg + 1024);   // 4x16x64 overlay
  if (lg == 0) SumS[p * 16 + lm][h] = sum;
  if (h == 1) {
    #pragma unroll
    for (int ds = 0; ds < 4; ++ds)
      #pragma unroll
      for (int j = 0; j < 4; ++j)
        CtxS[p][lg * 4 + j][ds * 16 + lm] = ctx[ds][j];
  }
  __syncthreads();

  if (h == 0) {
    float rcpj[4];
    #pragma unroll
    for (int j = 0; j < 4; ++j) {
      int r = p * 16 + lg * 4 + j;
      rcpj[j] = 1.0f / (SumS[r][0] + SumS[r][1]);
    }
    #pragma unroll
    for (int ds = 0; ds < 4; ++ds)
      #pragma unroll
      for (int j = 0; j < 4; ++j)
        Octx[((size_t)bh * NSQ + q0 + p * 16 + lg * 4 + j) * ND + ds * 16 + lm] =
            (ctx[ds][j] + CtxS[p][lg * 4 + j][ds * 16 + lm]) * rcpj[j];
  }

  // ---- weights out: wave writes its own 16 rows x its 512-kv half ----
  float* Owp = Ow + (size_t)bh * NSQ * NSKV + (size_t)(q0 + p * 16) * NSKV;
  for (int r = 0; r < 16; ++r) {
    float rr = 1.0f / (SumS[p * 16 + r][0] + SumS[p * 16 + r][1]);
    int kv = kvb + l * 8;
    short8 pv = *(const short8*)((char*)Ps + (p * 16 + r) * 2048 +
                                 ((kv * 2) ^ (r << 4)));
    f32x4 o1, o2;
    o1[0] = bf2f((unsigned short)pv[0]) * rr;
    o1[1] = bf2f((unsigned short)pv[1]) * rr;
    o1[2] = bf2f((unsigned short)pv[2]) * rr;
    o1[3] = bf2f((unsigned short)pv[3]) * rr;
    o2[0] = bf2f((unsigned short)pv[4]) * rr;
    o2[1] = bf2f((unsigned short)pv[5]) * rr;
    o2[2] = bf2f((unsigned short)pv[6]) * rr;
    o2[3] = bf2f((unsigned short)pv[7]) * rr;
    *(f32x4*)&Owp[(size_t)r * NSKV + kv]     = o1;
    *(f32x4*)&Owp[(size_t)r * NSKV + kv + 4] = o2;
  }
}

extern "C" void kernel_launch(void* const* d_in, const int* in_sizes, int n_in,
                              void* d_out, int out_size, void* d_ws, size_t ws_size,
                              hipStream_t stream) {
  const float* Q = (const float*)d_in[0];
  const float* K = (const float*)d_in[1];
  const float* V = (const float*)d_in[2];
  const int*   M = (const int*)d_in[3];
  const float* A = (const float*)d_in[4];
  float* ctx = (float*)d_out;
  float* wts = ctx + (size_t)NB * NH * NSQ * ND;  // outputs: (context, weights)
  dim3 grid(NB * NH * (NSQ / 64));                // 1024 blocks
  attn_fused<<<grid, dim3(512), 0, stream>>>(Q, K, V, M, A, ctx, wts);
}

// Round 19
// 174.359 us; speedup vs baseline: 1.3252x; 1.0534x over previous
//
#include <hip/hip_runtime.h>

#define NB 4
#define NH 16
#define NSQ 1024
#define NSKV 1024
#define ND 64

typedef __attribute__((ext_vector_type(8))) short short8;
typedef __attribute__((ext_vector_type(4))) float f32x4;
typedef __attribute__((ext_vector_type(4))) int int4v;
typedef __attribute__((ext_vector_type(4))) unsigned int uint4v;
typedef __attribute__((ext_vector_type(2))) unsigned int uint2v;

__device__ __forceinline__ unsigned int cvt_pk(float lo, float hi) {
  unsigned int r;
  asm("v_cvt_pk_bf16_f32 %0, %1, %2" : "=v"(r) : "v"(lo), "v"(hi));
  return r;
}
__device__ __forceinline__ float bf2f(unsigned short h) {
  return __uint_as_float(((unsigned int)h) << 16);
}
__device__ __forceinline__ void bar() { __builtin_amdgcn_s_barrier(); }
__device__ __forceinline__ void lgkm0() {
  asm volatile("s_waitcnt lgkmcnt(0)" ::: "memory");
}
// gfx950 cross-lane half-swaps (pure VALU, no LDS pipe) — R17-verified.
__device__ __forceinline__ void pl32(unsigned& a, unsigned& b) {
  asm("v_permlane32_swap_b32 %0, %1" : "+v"(a), "+v"(b));
}
__device__ __forceinline__ void pl16(unsigned& a, unsigned& b) {
  asm("v_permlane16_swap_b32 %0, %1" : "+v"(a), "+v"(b));
}

// SYMMETRIC BALANCED PHASES (replaces R11/R17 stagger): every interval,
// EVERY wave does {writeStage(chunk c+1 -> other buffer) + compute(chunk c)}
// for its own kv-half, with double-buffered K/V staging. Both waves on a
// SIMD carry identical ~2600cy mixed workloads -> when one stalls on its
// ds_read/MFMA chain the other always has independent issue work (the
// stagger left the stage-gang idle ~1400cy/interval). 1 barrier per 32-kv
// chunk. LDS = 160KB exactly: Ps 128K + 2 halves x 2 bufs x (K 4K + V 4K).
// R17-verified pieces verbatim: permlane V-transpose, permlane pf
// redistribution (no Ps read-back), mask-folded A-load, XCD clustering.
__global__ __launch_bounds__(512, 2)
void attn_fused(const float* __restrict__ Q, const float* __restrict__ K,
                const float* __restrict__ V, const int* __restrict__ M,
                const float* __restrict__ A, float* __restrict__ Octx,
                float* __restrict__ Ow)
{
  __shared__ unsigned short Ps[64 * 1024];           // 128 KB, rows 2048B, XOR (lm<<4)
  __shared__ __align__(16) unsigned char Stg[32768]; // 2 halves x 2 bufs x 8KB

  const int t  = threadIdx.x;
  const int w  = t >> 6;
  const int l  = t & 63;
  const int lg = l >> 4;       // 0..3
  const int lm = l & 15;
  const int p  = w & 3;        // q-row pair id
  const int h  = w >> 2;       // kv half
  const int g  = p * 64 + l;   // gang lane within half (0..255)

  // XCD clustering: each bh's 16 q-tiles land on ONE XCD (K/V L2-resident)
  const int bid = blockIdx.x;            // 1024 blocks
  const int y   = bid >> 3;
  const int qt  = y & 15;                // 16 q-tiles of 64 rows
  const int bh  = (bid & 7) * 8 + (y >> 4);
  const int b   = bh >> 4;
  const int q0  = qt * 64;
  const int kvb = h * 512;

  const float* Qp = Q + (size_t)bh * NSQ * ND;
  const float* Kp = K + (size_t)bh * NSKV * ND;
  const float* Vp = V + (size_t)bh * NSKV * ND;
  const float* Ap = A + (size_t)bh * NSQ * NSKV;
  const int*   Mp = M + (size_t)b  * NSQ * NSKV;

  const float C = 0.18033688011112042f;  // 0.125 * log2(e)

  // Q fragment (B operand of QK^T): lane holds Q[q0+p*16+lm][dc*32+lg*8+e]
  short8 qf[2];
  {
    const float* qr = Qp + (size_t)(q0 + p * 16 + lm) * ND + lg * 8;
    #pragma unroll
    for (int dc = 0; dc < 2; ++dc) {
      f32x4 x = *(const f32x4*)(qr + dc * 32);
      f32x4 y2 = *(const f32x4*)(qr + dc * 32 + 4);
      uint4v u;
      u[0] = cvt_pk(x[0], x[1]); u[1] = cvt_pk(x[2], x[3]);
      u[2] = cvt_pk(y2[0], y2[1]); u[3] = cvt_pk(y2[2], y2[3]);
      qf[dc] = __builtin_bit_cast(short8, u);
    }
  }

  f32x4 ctx[4];
  #pragma unroll
  for (int i = 0; i < 4; ++i) ctx[i] = (f32x4){0.f, 0.f, 0.f, 0.f};
  float sum = 0.f;

  f32x4 sk[2], sv[2];            // staging regs: one 32-kv chunk in flight
  f32x4 aA[2], aB[2];            // A (mask+scale folded), alternating buffers

  // chunk = 32 kv x 64 d = 2048 f32 contiguous; gang lane g: g*4 + i*1024
  auto issueStage = [&](int c) {
    int kv0 = kvb + c * 32;
    const float* kb = Kp + (size_t)kv0 * ND + g * 4;
    const float* vb = Vp + (size_t)kv0 * ND + g * 4;
    sk[0] = *(const f32x4*)kb;       sk[1] = *(const f32x4*)(kb + 1024);
    sv[0] = *(const f32x4*)vb;       sv[1] = *(const f32x4*)(vb + 1024);
  };
  // A with mask fold: r[j] = m ? a*C : -1.8e8 (exp2 underflows to exact 0)
  auto loadAF = [&](int c, f32x4* a) {
    int kv0 = kvb + c * 32;
    #pragma unroll
    for (int sub = 0; sub < 2; ++sub) {
      size_t off = (size_t)(q0 + p * 16 + lm) * NSKV + kv0 + sub * 16 + lg * 4;
      f32x4 av = *(const f32x4*)(Ap + off);
      int4v mv = *(const int4v*)(Mp + off);
      f32x4 r;
      #pragma unroll
      for (int j = 0; j < 4; ++j) r[j] = mv[j] ? av[j] * C : -1.8e8f;
      a[sub] = r;
    }
  };
  auto writeStage = [&](int buf) {
    unsigned char* KsB = Stg + h * 16384 + buf * 8192;  // [32][128B] XOR (row&7)<<4
    unsigned char* VtB = KsB + 4096;                    // [64 d][64B] XOR ((d>>1)&3)<<4
    #pragma unroll
    for (int i = 0; i < 2; ++i) {
      int f = g * 4 + i * 1024;
      int row = f >> 6;            // kv-local 0..31
      int cb  = (f & 63) * 2;      // byte col in 128B row (8B-aligned)
      uint2v u;
      u[0] = cvt_pk(sk[i][0], sk[i][1]);
      u[1] = cvt_pk(sk[i][2], sk[i][3]);
      *(uint2v*)(KsB + row * 128 + (cb ^ ((row & 7) << 4))) = u;
      // V: in-register 4x4 transpose (R17-verified butterfly) across lanes
      // {l,l+16,l+32,l+48}; post: reg j = V[kvbase+j][4x+m], one b64 write.
      unsigned r0 = __float_as_uint(sv[i][0]);
      unsigned r1 = __float_as_uint(sv[i][1]);
      unsigned r2 = __float_as_uint(sv[i][2]);
      unsigned r3 = __float_as_uint(sv[i][3]);
      pl32(r0, r2); pl32(r1, r3);
      pl16(r0, r1); pl16(r2, r3);
      int d = 4 * (l & 15) + (l >> 4);
      int kvbase = 4 * p + 16 * i;
      uint2v vu;
      vu[0] = cvt_pk(__uint_as_float(r0), __uint_as_float(r1));
      vu[1] = cvt_pk(__uint_as_float(r2), __uint_as_float(r3));
      *(uint2v*)(VtB + d * 64 + ((kvbase * 2) ^ (((d >> 1) & 3) << 4))) = vu;
    }
  };

  auto compute = [&](int c, int buf, const f32x4* a) {
    const unsigned char* KsB = Stg + h * 16384 + buf * 8192;
    const unsigned char* VtB = KsB + 4096;
    int kv0 = kvb + c * 32;
    const int ksw = (lm & 7) << 4;
    const int vsw = ((lm >> 1) & 3) << 4;
    short8 kf[4];
    #pragma unroll
    for (int sub = 0; sub < 2; ++sub)
      #pragma unroll
      for (int dc = 0; dc < 2; ++dc)
        kf[sub * 2 + dc] = *(const short8*)(
            KsB + (sub * 16 + lm) * 128 + ((dc * 64 + lg * 16) ^ ksw));
    short8 vf[4];
    #pragma unroll
    for (int ds = 0; ds < 4; ++ds)
      vf[ds] = *(const short8*)(VtB + (ds * 16 + lm) * 64 + ((lg * 16) ^ vsw));

    __builtin_amdgcn_s_setprio(1);
    // QK^T (A=K,B=Q): acc[j] = logit(q=lm, kv=kv0+sub*16+lg*4+j)
    unsigned s0, s1, s2, s3;
    {
      f32x4 acc = (f32x4){0.f, 0.f, 0.f, 0.f};
      acc = __builtin_amdgcn_mfma_f32_16x16x32_bf16(kf[0], qf[0], acc, 0, 0, 0);
      acc = __builtin_amdgcn_mfma_f32_16x16x32_bf16(kf[1], qf[1], acc, 0, 0, 0);
      float pe[4];
      #pragma unroll
      for (int j = 0; j < 4; ++j) {
        pe[j] = exp2f(fmaf(acc[j], C, a[0][j]));   // masked -> exact 0
        sum += pe[j];
      }
      s0 = cvt_pk(pe[0], pe[1]); s1 = cvt_pk(pe[2], pe[3]);
      uint2v u2; u2[0] = s0; u2[1] = s1;
      *(uint2v*)((char*)Ps + (p * 16 + lm) * 2048 +
                 (((kv0 + lg * 4) * 2) ^ (lm << 4))) = u2;
    }
    {
      f32x4 acc = (f32x4){0.f, 0.f, 0.f, 0.f};
      acc = __builtin_amdgcn_mfma_f32_16x16x32_bf16(kf[2], qf[0], acc, 0, 0, 0);
      acc = __builtin_amdgcn_mfma_f32_16x16x32_bf16(kf[3], qf[1], acc, 0, 0, 0);
      float pe[4];
      #pragma unroll
      for (int j = 0; j < 4; ++j) {
        pe[j] = exp2f(fmaf(acc[j], C, a[1][j]));
        sum += pe[j];
      }
      s2 = cvt_pk(pe[0], pe[1]); s3 = cvt_pk(pe[2], pe[3]);
      uint2v u2; u2[0] = s2; u2[1] = s3;
      *(uint2v*)((char*)Ps + (p * 16 + lm) * 2048 +
                 (((kv0 + 16 + lg * 4) * 2) ^ (lm << 4))) = u2;
    }
    // pf via permlane redistribution (R17-verified; no Ps read-back)
    pl32(s0, s2); pl32(s1, s3);
    pl16(s0, s2); pl16(s1, s3);
    uint4v pu; pu[0] = s0; pu[1] = s1; pu[2] = s2; pu[3] = s3;
    short8 pf = __builtin_bit_cast(short8, pu);
    #pragma unroll
    for (int ds = 0; ds < 4; ++ds)
      ctx[ds] = __builtin_amdgcn_mfma_f32_16x16x32_bf16(pf, vf[ds], ctx[ds], 0, 0, 0);
    __builtin_amdgcn_s_setprio(0);
  };

  // ---- prologue: buf0 <- chunk0; chunk1 + A0/A1 in flight ----
  issueStage(0);
  loadAF(0, aA);
  writeStage(0);                 // vmcnt wait on chunk0 loads
  issueStage(1);                 // chunk1 loads in flight
  loadAF(1, aB);
  lgkm0(); bar();

  // ---- symmetric sweep: 16 chunks of 32 kv per half, 1 barrier/chunk ----
  for (int c = 0; c < 16; c += 2) {
    int n2 = (c + 2 > 15) ? 15 : c + 2;
    int n3 = (c + 3 > 15) ? 15 : c + 3;
    // interval A: stage chunk c+1 -> buf1 ; compute chunk c from buf0
    writeStage(1);               // sk holds chunk c+1 (counted vmcnt)
    issueStage(n2);              // chunk c+2 loads in flight
    compute(c, 0, aA);
    loadAF(n2, aA);              // consumed 2 intervals later
    lgkm0(); bar();
    // interval B: stage chunk c+2 -> buf0 ; compute chunk c+1 from buf1
    writeStage(0);               // sk holds chunk c+2
    issueStage(n3);
    compute(c + 1, 1, aB);
    loadAF(n3, aB);
    lgkm0(); bar();
  }

  // ---- merge halves (staging regions dead after this barrier) ----
  sum += __shfl_xor(sum, 16);
  sum += __shfl_xor(sum, 32);
  __syncthreads();

  float (*SumS)[2]      = (float(*)[2])Stg;                 // 64x2 overlay
  float (*CtxS)[16][64] = (float(*)[16][64])(Stg + 1024);   // 4x16x64 overlay
  if (lg == 0) SumS[p * 16 + lm][h] = sum;
  if (h == 1) {
    #pragma unroll
    for (int ds = 0; ds < 4; ++ds)
      #pragma unroll
      for (int j = 0; j < 4; ++j)
        CtxS[p][lg * 4 + j][ds * 16 + lm] = ctx[ds][j];
  }
  __syncthreads();

  if (h == 0) {
    float rcpj[4];
    #pragma unroll
    for (int j = 0; j < 4; ++j) {
      int r = p * 16 + lg * 4 + j;
      rcpj[j] = 1.0f / (SumS[r][0] + SumS[r][1]);
    }
    #pragma unroll
    for (int ds = 0; ds < 4; ++ds)
      #pragma unroll
      for (int j = 0; j < 4; ++j)
        Octx[((size_t)bh * NSQ + q0 + p * 16 + lg * 4 + j) * ND + ds * 16 + lm] =
            (ctx[ds][j] + CtxS[p][lg * 4 + j][ds * 16 + lm]) * rcpj[j];
  }

  // ---- weights out: wave writes its own 16 rows x its 512-kv half ----
  float* Owp = Ow + (size_t)bh * NSQ * NSKV + (size_t)(q0 + p * 16) * NSKV;
  for (int r = 0; r < 16; ++r) {
    float rr = 1.0f / (SumS[p * 16 + r][0] + SumS[p * 16 + r][1]);
    int kv = kvb + l * 8;
    short8 pv = *(const short8*)((char*)Ps + (p * 16 + r) * 2048 +
                                 ((kv * 2) ^ (r << 4)));
    f32x4 o1, o2;
    o1[0] = bf2f((unsigned short)pv[0]) * rr;
    o1[1] = bf2f((unsigned short)pv[1]) * rr;
    o1[2] = bf2f((unsigned short)pv[2]) * rr;
    o1[3] = bf2f((unsigned short)pv[3]) * rr;
    o2[0] = bf2f((unsigned short)pv[4]) * rr;
    o2[1] = bf2f((unsigned short)pv[5]) * rr;
    o2[2] = bf2f((unsigned short)pv[6]) * rr;
    o2[3] = bf2f((unsigned short)pv[7]) * rr;
    *(f32x4*)&Owp[(size_t)r * NSKV + kv]     = o1;
    *(f32x4*)&Owp[(size_t)r * NSKV + kv + 4] = o2;
  }
}

extern "C" void kernel_launch(void* const* d_in, const int* in_sizes, int n_in,
                              void* d_out, int out_size, void* d_ws, size_t ws_size,
                              hipStream_t stream) {
  const float* Q = (const float*)d_in[0];
  const float* K = (const float*)d_in[1];
  const float* V = (const float*)d_in[2];
  const int*   M = (const int*)d_in[3];
  const float* A = (const float*)d_in[4];
  float* ctx = (float*)d_out;
  float* wts = ctx + (size_t)NB * NH * NSQ * ND;  // outputs: (context, weights)
  dim3 grid(NB * NH * (NSQ / 64));                // 1024 blocks
  attn_fused<<<grid, dim3(512), 0, stream>>>(Q, K, V, M, A, ctx, wts);
}